// Round 17
// baseline (359.055 us; speedup 1.0000x reference)
//
#include <hip/hip_runtime.h>
#include <hip/hip_bf16.h>
#include <cstdint>
#include <cstdio>

typedef float f32x4 __attribute__((ext_vector_type(4)));
typedef float f32x2 __attribute__((ext_vector_type(2)));
typedef short s16x8 __attribute__((ext_vector_type(8)));   // 8 bf16 (4 VGPRs) MFMA operand
typedef unsigned int u32x2 __attribute__((ext_vector_type(2)));

__device__ __forceinline__ float us2f(unsigned short u){
  union { unsigned int i; float f; } v; v.i = ((unsigned int)u) << 16; return v.f;
}
__device__ __forceinline__ unsigned short f2us(float f){   // RNE f32->bf16
  union { float f; unsigned int i; } v; v.f = f;
  unsigned int r = v.i + 0x7fffu + ((v.i >> 16) & 1u);
  return (unsigned short)(r >> 16);
}
// direct global->LDS DMA, 16B per lane; LDS dest must be linear (base + lane*16)
__device__ __forceinline__ void gload_lds16(const void* g, void* l){
  __builtin_amdgcn_global_load_lds(
      (const __attribute__((address_space(1))) unsigned int*)g,
      (__attribute__((address_space(3))) unsigned int*)l, 16, 0, 0);
}

// Decay poly constant term: e^y ~= K0 + c1*y ... (Taylor at y0=-0.18, deg 3), y = w*dt in [-0.36,0]
#define PK0 0.999962f

// ---------------- prep: cast/concat weights to bf16 (row-major, coalesced), poly coeffs --------
__global__ __launch_bounds__(256)
void prep_k(const float* __restrict__ x,
            const float* __restrict__ W_in_f, const float* __restrict__ W_in_b,
            const float* __restrict__ Wx_f,   const float* __restrict__ Wx_b,
            const float* __restrict__ Wdt_f,  const float* __restrict__ Wdt_b,
            const float* __restrict__ Wout_f, const float* __restrict__ Wout_b,
            const float* __restrict__ Alog_f, const float* __restrict__ Alog_b,
            const float* __restrict__ bdt_f,  const float* __restrict__ bdt_b,
            unsigned short* __restrict__ W1cat, unsigned short* __restrict__ Wxpad,
            unsigned short* __restrict__ Wdtb,  unsigned short* __restrict__ Woutcat,
            float* __restrict__ A2, float* __restrict__ bdtcat,
            unsigned short* __restrict__ xbf, float* __restrict__ Cf)
{
  long i = (long)blockIdx.x * 256 + threadIdx.x;
  if (i < 4194304) {            // xbf = bf16(x), 8192x512
    xbf[i] = f2us(x[i]); return;
  }
  i -= 4194304;
  if (i < 2097152) {            // W1cat[n][k], 4096x512 (f rows 0-2047, b rows 2048-4095)
    int n = (int)(i >> 9), k = (int)(i & 511);
    float v = (n < 2048) ? W_in_f[(long)n*512 + k] : W_in_b[(long)(n-2048)*512 + k];
    W1cat[i] = f2us(v); return;
  }
  i -= 2097152;
  if (i < 262144) {             // Wxpad[dir][128][1024], rows>=96 zero
    int dir = (int)(i >> 17); long r = i & 131071; int n = (int)(r >> 10), k = (int)(r & 1023);
    const float* Wx = dir ? Wx_b : Wx_f;
    Wxpad[(long)dir*131072 + r] = f2us(n < 96 ? Wx[(long)n*1024 + k] : 0.f); return;
  }
  i -= 262144;
  if (i < 131072) {             // Wdtb[dir][1024][64]
    int dir = (int)(i >> 16); long r = i & 65535;
    Wdtb[i] = f2us((dir ? Wdt_b : Wdt_f)[r]); return;
  }
  i -= 131072;
  if (i < 1048576) {            // Woutcat[n][2048]: k<1024 from f, else b
    int n = (int)(i >> 11), k = (int)(i & 2047);
    float v = (k < 1024) ? Wout_f[(long)n*1024 + k] : Wout_b[(long)n*1024 + (k-1024)];
    Woutcat[i] = f2us(v); return;
  }
  i -= 1048576;
  if (i < 32768) {              // A2[dir][m][d] = -exp(Alog[d][m]) * log2(e)  (scan2 only)
    int dir = (int)(i >> 14); long r = i & 16383; int m = (int)(r >> 4), d = (int)(r & 15);
    const float* Al = dir ? Alog_b : Alog_f;
    A2[i] = -__expf(Al[(long)d*1024 + m]) * 1.4426950408889634f; return;
  }
  i -= 32768;
  if (i < 2048) {               // bdtcat[dir][1024]
    int dir = (int)(i >> 10), m = (int)(i & 1023);
    bdtcat[i] = (dir ? bdt_b : bdt_f)[m]; return;
  }
  i -= 2048;
  if (i < 98304) {              // Cf[dir][m][48]: decay poly coeffs c1[16],c2[16],c3[16]
    int dir = (int)(i / 49152); long r = i % 49152;
    int m = (int)(r / 48), j = (int)(r % 48);
    int k = j >> 4, d = j & 15;
    const float* Al = dir ? Alog_b : Alog_f;
    const float w = -__expf(Al[(long)d*1024 + m]);     // dA = exp(w*dt), w in [-1.7,-0.6]
    float c;
    if (k == 0)      c = 0.999150f * w;                // e^y Taylor@-0.18 deg-3 coeffs
    else if (k == 1) c = 0.492809f * w * w;
    else             c = 0.139212f * w * w * w;
    Cf[(long)dir*49152 + (long)m*48 + (k << 4) + d] = c;
    return;
  }
}

// ---------------- ring-4 counted-vmcnt bf16 MFMA GEMM: 128x128 tile, BK=64 ----------------------
// 4 LDS slots (one K-tile each, A+B 32KB), prefetch distance 3, raw s_barrier + counted
// s_waitcnt vmcnt(N) — loads stay in flight across barriers, NEVER drained to 0 mid-loop (T4).
// Slot discipline: iter kt computes slot kt&3, stages kt+3 into (kt+3)&3 == (kt-1)&3 (whose
// reads all retired before last iter's MFMAs; this iter's barrier makes that block-wide).
// vmcnt: 8 loads/slot, in-order retirement => steady vmcnt(16) guarantees slot kt landed
// while slots kt+1, kt+2 remain in flight. Tail: vmcnt(8) at NK-2, vmcnt(0) at NK-1.
// Same swizzle (G4/rule#21), fragment layout and epilogue as the proven gemm_bt.
// OUT_MODE: 1 = bf16 softplus(acc+bias[col]), 2 = f32,
//           3 = bf16 + fp32 B/C side-write, 4 = bf16 with silu applied iff (col>>10)&1
template<int OUT_MODE>
__global__ __launch_bounds__(256)
void gemm_ring(const unsigned short* __restrict__ Ap, const unsigned short* __restrict__ Bp,
               void* __restrict__ Cp, const float* __restrict__ biasp,
               float* __restrict__ bcf,
               int K, int lda, int ldb, int ldc,
               long az, long bz, long cz, int biasz)
{
  const int z   = blockIdx.z;
  const int tid = threadIdx.x;
  const int bm  = blockIdx.x, bn = blockIdx.y;

  __shared__ __align__(16) unsigned short Ash[4][128][64];   // 64KB
  __shared__ __align__(16) unsigned short Bsh[4][128][64];   // 64KB

  const int wave = tid >> 6, lane = tid & 63;
  const int wr = (wave >> 1) << 6, wc = (wave & 1) << 6;
  const int fr = lane & 15, fs = lane >> 4;

  const int rr  = tid >> 3;                 // row 0..31 (+32/round)
  const int csp = tid & 7;                  // linear LDS col-slot
  const int csg = ((csp ^ (rr & 7)) << 3);  // pre-swizzled source col (elements)

  const unsigned short* Ag = Ap + (long)z * az;
  const unsigned short* Bg = Bp + (long)z * bz;

  const long abase = (long)(bm*128 + rr)*lda + csg;
  const long bbase = (long)(bn*128 + rr)*ldb + csg;

  f32x4 acc[4][4];
  #pragma unroll
  for (int i=0;i<4;i++)
    #pragma unroll
    for (int j=0;j<4;j++) acc[i][j] = (f32x4){0.f,0.f,0.f,0.f};

  const int NK = K >> 6;

  auto stage = [&](int slot, int ks){      // 8 gload_lds16 per thread (A 4 + B 4)
    const long k0 = (long)ks << 6;
    #pragma unroll
    for (int r=0;r<4;r++){
      gload_lds16(Ag + abase + (long)(r*32)*lda + k0, &Ash[slot][rr + r*32][csp << 3]);
      gload_lds16(Bg + bbase + (long)(r*32)*ldb + k0, &Bsh[slot][rr + r*32][csp << 3]);
    }
  };
  auto compute = [&](int slot){
    #pragma unroll
    for (int sub=0; sub<2; ++sub){
      s16x8 af[4], bfv[4];
      #pragma unroll
      for (int i=0;i<4;i++){
        const int ar = wr + i*16 + fr;
        af[i]  = *(const s16x8*)&Ash[slot][ar][(((sub<<2)+fs) ^ (fr&7)) << 3];
        const int br = wc + i*16 + fr;
        bfv[i] = *(const s16x8*)&Bsh[slot][br][(((sub<<2)+fs) ^ (fr&7)) << 3];
      }
      #pragma unroll
      for (int i=0;i<4;i++)
        #pragma unroll
        for (int j=0;j<4;j++)
          acc[i][j] = __builtin_amdgcn_mfma_f32_16x16x32_bf16(bfv[j], af[i], acc[i][j], 0, 0, 0);
    }
  };

  // prologue: stage up to 3 K-tiles ahead
  const int NP = NK < 3 ? NK : 3;
  for (int t = 0; t < NP; ++t) stage(t & 3, t);

  for (int kt = 0; kt < NK; ++kt){
    // counted wait: slot kt's 8 loads landed; later slots stay in flight
    if (kt < NK - 2)       asm volatile("s_waitcnt vmcnt(16)" ::: "memory");
    else if (kt == NK - 2) asm volatile("s_waitcnt vmcnt(8)"  ::: "memory");
    else                   asm volatile("s_waitcnt vmcnt(0)"  ::: "memory");
    __builtin_amdgcn_s_barrier();          // raw barrier: no implicit vmcnt(0) drain
    if (kt + 3 < NK) stage((kt + 3) & 3, kt + 3);
    compute(kt & 3);
  }

  // epilogue — swapped D layout: row = lane&15 (within i-tile), cols = (lane>>4)*4 + e (j-tile)
  #pragma unroll
  for (int i=0;i<4;i++){
    const int row = bm*128 + wr + i*16 + fr;
    #pragma unroll
    for (int j=0;j<4;j++){
      const int c0 = bn*128 + wc + j*16 + (fs << 2);
      f32x4 v = acc[i][j];
      const long cbase = (long)z*cz + (long)row*ldc + c0;
      if (OUT_MODE == 2){
        *(f32x4*)((float*)Cp + cbase) = v;
      } else if (OUT_MODE == 1){
        const f32x4 b4 = *(const f32x4*)(biasp + z*biasz + c0);
        u32x2 o;
        unsigned short s[4];
        #pragma unroll
        for (int e=0;e<4;e++){
          float t = v[e] + b4[e];
          t = fmaxf(t, 0.f) + log1pf(__expf(-fabsf(t)));   // softplus, stable
          s[e] = f2us(t);
        }
        o[0] = (unsigned int)s[0] | ((unsigned int)s[1] << 16);
        o[1] = (unsigned int)s[2] | ((unsigned int)s[3] << 16);
        *(u32x2*)((unsigned short*)Cp + cbase) = o;
      } else {
        if (OUT_MODE == 4 && ((c0 >> 10) & 1)){
          #pragma unroll
          for (int e=0;e<4;e++) v[e] = v[e] / (1.f + __expf(-v[e]));   // silu(z) fused
        }
        u32x2 o;
        o[0] = (unsigned int)f2us(v[0]) | ((unsigned int)f2us(v[1]) << 16);
        o[1] = (unsigned int)f2us(v[2]) | ((unsigned int)f2us(v[3]) << 16);
        *(u32x2*)((unsigned short*)Cp + cbase) = o;
        if (OUT_MODE == 3 && c0 >= 64 && c0 < 96){
          // side-write raw fp32 B/C rows: BCf[z][row][c0-64 .. +3]
          *(f32x4*)(bcf + ((long)z*8192 + row)*32 + (c0 - 64)) = v;
        }
      }
    }
  }
}

// ---------------- depthwise causal/anticausal conv (K=4) + SiLU, 8 channels/thread -------------
__global__ __launch_bounds__(256)
void conv_silu_k(const unsigned short* __restrict__ xz,
                 const float* __restrict__ wf, const float* __restrict__ cbf,
                 const float* __restrict__ wb, const float* __restrict__ cbb,
                 unsigned short* __restrict__ xbc)
{
  const int tid = threadIdx.x;
  const long tok = blockIdx.x;                       // 0..8191
  const int l   = (int)(tok & 2047);
  const int dir = tid >> 7;
  const int mg  = (tid & 127) << 3;                  // base of 8 contiguous channels
  const float* w  = dir ? wb  : wf;
  const float* cb = dir ? cbb : cbf;
  const long rowb = tok << 12;                       // *4096
  const int  xcol = (dir << 11) + mg;                // xb_f cols [0,1024), xb_b [2048,3072)

  f32x4 wv[8];
  #pragma unroll
  for (int e=0;e<8;e++) wv[e] = *(const f32x4*)(w + (mg + e)*4);
  const f32x4 cb0 = *(const f32x4*)(cb + mg);
  const f32x4 cb1 = *(const f32x4*)(cb + mg + 4);

  float acc[8];
  #pragma unroll
  for (int e=0;e<4;e++){ acc[e]=cb0[e]; acc[4+e]=cb1[e]; }

  #pragma unroll
  for (int k=0;k<4;k++){
    const int off = dir ? (3 - k) : (k - 3);         // pos - l
    const int pos = l + off;
    if (pos >= 0 && pos < 2048){                     // wave-uniform predicate
      const s16x8 xv = *(const s16x8*)(xz + rowb + ((long)off << 12) + xcol);
      #pragma unroll
      for (int e=0;e<8;e++)
        acc[e] = __builtin_fmaf(wv[e][k], us2f((unsigned short)xv[e]), acc[e]);
    }
  }
  s16x8 out;
  #pragma unroll
  for (int e=0;e<8;e++){
    const float s = acc[e] / (1.f + __expf(-acc[e]));
    out[e] = (short)f2us(s);
  }
  *(s16x8*)(xbc + tok*2048 + (dir << 10) + mg) = out;
}

// ---------------- chunked selective scan: 64 chunks x 32 steps, 1 channel/thread ---------------
#define SCHUNK 32
#define NCHUNK 64

// pass 1: per-chunk local scan + S = sum(dt). Packed f32x2 math; prefetch depth 2.
__global__ __launch_bounds__(256)
void scan1_k(const unsigned short* __restrict__ dtb, const unsigned short* __restrict__ xbc,
             const float* __restrict__ BCf, const float* __restrict__ Cf,
             unsigned short* __restrict__ hloc, float* __restrict__ Ssum)
{
  const int tidx = threadIdx.x;
  const int cb = blockIdx.x, c = blockIdx.y, bz = blockIdx.z;
  const int b = bz >> 1, dir = bz & 1;
  const int m = cb*256 + tidx;

  f32x2 C1v[8], C2v[8], C3v[8];
  { const f32x4* p = (const f32x4*)(Cf + ((long)dir*1024 + m)*48);
    #pragma unroll
    for (int q=0;q<4;q++){
      f32x4 v1=p[q], v2=p[q+4], v3=p[q+8];
      C1v[2*q]   = (f32x2){v1[0], v1[1]};  C1v[2*q+1] = (f32x2){v1[2], v1[3]};
      C2v[2*q]   = (f32x2){v2[0], v2[1]};  C2v[2*q+1] = (f32x2){v2[2], v2[3]};
      C3v[2*q]   = (f32x2){v3[0], v3[1]};  C3v[2*q+1] = (f32x2){v3[2], v3[3]};
    } }
  const f32x2 k0v = {PK0, PK0};

  const int  l0 = dir ? (2047 - c*SCHUNK) : (c*SCHUNK);
  const int  ls = dir ? -1 : 1;
  const long tok0 = (long)b*2048 + l0;

  __shared__ float Bs[SCHUNK][16];
  if (tidx < 128){
    const int r = tidx >> 2, c4 = (tidx & 3) << 2;
    *(f32x4*)&Bs[r][c4] =
        *(const f32x4*)(BCf + ((long)dir*8192 + tok0 + (long)ls*r)*32 + c4);
  }
  __syncthreads();

  const long dstp = (long)ls*1024, xstp = (long)ls*2048;
  const unsigned short* dt0 = dtb + ((long)dir << 23) + tok0*1024 + m;
  const unsigned short* xv0 = xbc + tok0*2048 + (dir << 10) + m;
  const unsigned short* dt1 = dt0 + dstp;
  const unsigned short* xv1 = xv0 + xstp;

  f32x2 h2[8];
  #pragma unroll
  for (int p=0;p<8;p++) h2[p] = (f32x2){0.f, 0.f};
  float S = 0.f;

  auto body = [&](float dt, float xv, int t){
    S += dt;
    const float u = dt * xv;
    const float dt2 = dt*dt, dt3 = dt2*dt;
    const f32x2 dtv = {dt, dt}, dt2v = {dt2, dt2}, dt3v = {dt3, dt3}, uv = {u, u};
    const f32x2* b2 = (const f32x2*)&Bs[t][0];
    #pragma unroll
    for (int p=0;p<8;p++){
      f32x2 a = __builtin_elementwise_fma(C1v[p], dtv, k0v);
      a = __builtin_elementwise_fma(C2v[p], dt2v, a);
      a = __builtin_elementwise_fma(C3v[p], dt3v, a);
      h2[p] = __builtin_elementwise_fma(a, h2[p], uv * b2[p]);
    }
  };

  unsigned short dA = *dt0, xA = *xv0, dB = *dt1, xB = *xv1;   // steps t, t+1
  for (int t=0; t<SCHUNK; t+=2){
    const float dtA = us2f(dA), xvA = us2f(xA);
    dt0 += 2*dstp; xv0 += 2*xstp;
    dA = *dt0; xA = *xv0;                 // prefetch t+2 (edge reads stay inside d_ws)
    body(dtA, xvA, t);
    const float dtB = us2f(dB), xvB = us2f(xB);
    dt1 += 2*dstp; xv1 += 2*xstp;
    dB = *dt1; xB = *xv1;                 // prefetch t+3
    body(dtB, xvB, t+1);
  }
  const long o = (((long)bz * NCHUNK) + c)*1024 + m;
  s16x8 hv0, hv1;
  #pragma unroll
  for (int e=0;e<4;e++){
    hv0[2*e]   = (short)f2us(h2[e][0]);     hv0[2*e+1] = (short)f2us(h2[e][1]);
    hv1[2*e]   = (short)f2us(h2[4+e][0]);   hv1[2*e+1] = (short)f2us(h2[4+e][1]);
  }
  *(s16x8*)(hloc + (o << 4))     = hv0;
  *(s16x8*)(hloc + (o << 4) + 8) = hv1;
  Ssum[o] = S;
}

// pass 2: chunk recurrence; rewrites hloc in place with h_start per chunk (bf16)
__global__ __launch_bounds__(256)
void scan2_k(const float* __restrict__ A2, const float* __restrict__ Ssum,
             unsigned short* __restrict__ hloc)
{
  const long idx = (long)blockIdx.x*256 + threadIdx.x;   // 8*16384
  const long bz = idx >> 14; const int r = (int)(idx & 16383);
  const int dir = (int)(bz & 1);
  const float a2 = A2[((long)dir << 14) + r];
  const long base = bz * NCHUNK;
  float hs = 0.f;
  float hlN = us2f(hloc[base*16384 + r]);
  float SN  = Ssum[base*1024 + (r >> 4)];
  for (int c=0;c<NCHUNK;c++){
    const float hl = hlN, Sv = SN;
    const int cn = (c+1 < NCHUNK) ? c+1 : c;             // clamped prefetch
    hlN = us2f(hloc[(base+cn)*16384 + r]);
    SN  = Ssum[(base+cn)*1024 + (r >> 4)];
    const float P = __builtin_amdgcn_exp2f(a2 * Sv);     // range [-4,0]: keep HW exp2
    hloc[(base+c)*16384 + r] = f2us(hs);
    hs = __builtin_fmaf(P, hs, hl);
  }
}

// pass 3: full scan, fused +D*x, *pre-silu'd gate, bf16 y; packed f32x2; prefetch depth 2.
__global__ __launch_bounds__(256)
void scan3_k(const unsigned short* __restrict__ dtb, const unsigned short* __restrict__ xbc,
             const float* __restrict__ BCf, const float* __restrict__ Cf,
             const unsigned short* __restrict__ hstart, const unsigned short* __restrict__ xz,
             const float* __restrict__ D_f, const float* __restrict__ D_b,
             unsigned short* __restrict__ ybuf)
{
  const int tidx = threadIdx.x;
  const int cb = blockIdx.x, c = blockIdx.y, bz = blockIdx.z;
  const int b = bz >> 1, dir = bz & 1;
  const int m = cb*256 + tidx;

  f32x2 C1v[8], C2v[8], C3v[8];
  { const f32x4* p = (const f32x4*)(Cf + ((long)dir*1024 + m)*48);
    #pragma unroll
    for (int q=0;q<4;q++){
      f32x4 v1=p[q], v2=p[q+4], v3=p[q+8];
      C1v[2*q]   = (f32x2){v1[0], v1[1]};  C1v[2*q+1] = (f32x2){v1[2], v1[3]};
      C2v[2*q]   = (f32x2){v2[0], v2[1]};  C2v[2*q+1] = (f32x2){v2[2], v2[3]};
      C3v[2*q]   = (f32x2){v3[0], v3[1]};  C3v[2*q+1] = (f32x2){v3[2], v3[3]};
    } }
  const f32x2 k0v = {PK0, PK0};
  const float Dm = (dir ? D_b : D_f)[m];

  const int  l0 = dir ? (2047 - c*SCHUNK) : (c*SCHUNK);
  const int  ls = dir ? -1 : 1;
  const long tok0 = (long)b*2048 + l0;

  __shared__ float BC[SCHUNK][32];    // [t][0-15 B, 16-31 C]
  { const int r = tidx >> 3, c4 = (tidx & 7) << 2;
    *(f32x4*)&BC[r][c4] =
        *(const f32x4*)(BCf + ((long)dir*8192 + tok0 + (long)ls*r)*32 + c4); }

  f32x2 h2[8];
  { const long o = ((((long)bz*NCHUNK) + c)*1024 + m) << 4;
    s16x8 hv0 = *(const s16x8*)(hstart + o);
    s16x8 hv1 = *(const s16x8*)(hstart + o + 8);
    #pragma unroll
    for (int e=0;e<4;e++){
      h2[e]   = (f32x2){us2f((unsigned short)hv0[2*e]), us2f((unsigned short)hv0[2*e+1])};
      h2[4+e] = (f32x2){us2f((unsigned short)hv1[2*e]), us2f((unsigned short)hv1[2*e+1])};
    } }
  __syncthreads();

  const long dstp = (long)ls*1024, xstp = (long)ls*2048, zstp = (long)ls << 12;
  const unsigned short* dt0 = dtb + ((long)dir << 23) + tok0*1024 + m;
  const unsigned short* xv0 = xbc + tok0*2048 + (dir << 10) + m;
  const unsigned short* zp0 = xz  + (tok0 << 12) + (dir << 11) + 1024 + m;
  const unsigned short* dt1 = dt0 + dstp;
  const unsigned short* xv1 = xv0 + xstp;
  const unsigned short* zp1 = zp0 + zstp;
  unsigned short*       yp  = ybuf + tok0*2048 + (dir << 10) + m;

  auto body = [&](float dt, float xv, float gate, int t){
    const float u = dt * xv;
    const float dt2 = dt*dt, dt3 = dt2*dt;
    const f32x2 dtv = {dt, dt}, dt2v = {dt2, dt2}, dt3v = {dt3, dt3}, uv = {u, u};
    const f32x2* bc2 = (const f32x2*)&BC[t][0];    // B pairs [0..7], C pairs [8..15]
    f32x2 y2a = {0.f, 0.f}, y2b = {0.f, 0.f};
    #pragma unroll
    for (int p=0;p<8;p++){
      f32x2 a = __builtin_elementwise_fma(C1v[p], dtv, k0v);
      a = __builtin_elementwise_fma(C2v[p], dt2v, a);
      a = __builtin_elementwise_fma(C3v[p], dt3v, a);
      h2[p] = __builtin_elementwise_fma(a, h2[p], uv * bc2[p]);
      if (p & 1) y2b = __builtin_elementwise_fma(h2[p], bc2[8+p], y2b);
      else       y2a = __builtin_elementwise_fma(h2[p], bc2[8+p], y2a);
    }
    const float y = ((y2a[0] + y2a[1]) + (y2b[0] + y2b[1])) + Dm * xv;
    *yp = f2us(y * gate);
    yp += xstp;
  };

  unsigned short dA = *dt0, xA = *xv0, zA = *zp0;   // step t
  unsigned short dB = *dt1, xB = *xv1, zB = *zp1;   // step t+1
  for (int t=0; t<SCHUNK; t+=2){
    const float dtA = us2f(dA), xvA = us2f(xA), gA = us2f(zA);
    dt0 += 2*dstp; xv0 += 2*xstp; zp0 += 2*zstp;
    dA = *dt0; xA = *xv0; zA = *zp0;      // prefetch t+2 (edge reads stay inside d_ws)
    body(dtA, xvA, gA, t);
    const float dtB = us2f(dB), xvB = us2f(xB), gB = us2f(zB);
    dt1 += 2*dstp; xv1 += 2*xstp; zp1 += 2*zstp;
    dB = *dt1; xB = *xv1; zB = *zp1;      // prefetch t+3
    body(dtB, xvB, gB, t+1);
  }
}

// ---------------- host launcher ----------------------------------------------------------------
extern "C" void kernel_launch(void* const* d_in, const int* in_sizes, int n_in,
                              void* d_out, int out_size, void* d_ws, size_t ws_size,
                              hipStream_t stream)
{
  const float* x      = (const float*)d_in[0];
  const float* W_in_f = (const float*)d_in[1];
  const float* convw_f= (const float*)d_in[2];
  const float* convb_f= (const float*)d_in[3];
  const float* Alog_f = (const float*)d_in[4];
  const float* D_f    = (const float*)d_in[5];
  const float* Wx_f   = (const float*)d_in[6];
  const float* Wdt_f  = (const float*)d_in[7];
  const float* bdt_f  = (const float*)d_in[8];
  const float* Wout_f = (const float*)d_in[9];
  const float* W_in_b = (const float*)d_in[10];
  const float* convw_b= (const float*)d_in[11];
  const float* convb_b= (const float*)d_in[12];
  const float* Alog_b = (const float*)d_in[13];
  const float* D_b    = (const float*)d_in[14];
  const float* Wx_b   = (const float*)d_in[15];
  const float* Wdt_b  = (const float*)d_in[16];
  const float* bdt_b  = (const float*)d_in[17];
  const float* Wout_b = (const float*)d_in[18];

  char* w = (char*)d_ws;
  auto carve = [&](size_t bytes) -> char* {
    char* p = w; w += (bytes + 255) & ~(size_t)255; return p;
  };
  unsigned short* W1cat   = (unsigned short*)carve(4096ULL*512*2);
  unsigned short* Wxpad   = (unsigned short*)carve(2ULL*128*1024*2);
  unsigned short* Wdtb    = (unsigned short*)carve(2ULL*1024*64*2);
  unsigned short* Woutcat = (unsigned short*)carve(512ULL*2048*2);
  float*          A2      = (float*)carve(2ULL*1024*16*4);
  float*          bdtcat  = (float*)carve(2048ULL*4);
  float*          Cf      = (float*)carve(2ULL*1024*48*4);
  float*          BCf     = (float*)carve(2ULL*8192*32*4);
  unsigned short* xz      = (unsigned short*)carve(8192ULL*4096*2);
  unsigned short* xbc     = (unsigned short*)carve(8192ULL*2048*2);
  unsigned short* proj    = (unsigned short*)carve(2ULL*8192*128*2);
  unsigned short* dtb     = (unsigned short*)carve(2ULL*8192*1024*2);
  unsigned short* ybuf    = (unsigned short*)carve(8192ULL*2048*2);
  unsigned short* hloc    = (unsigned short*)carve(8ULL*NCHUNK*1024*16*2);
  float*          Ssum    = (float*)carve(8ULL*NCHUNK*1024*4);
  // xbf aliases ybuf: xbf lifetime = prep->GEMM1, ybuf lifetime = scan3->GEMM3 (disjoint)
  unsigned short* xbf     = ybuf;

  if ((size_t)(w - (char*)d_ws) > ws_size) {
    fprintf(stderr, "kernel_launch: ws too small (%zu needed, %zu given)\n",
            (size_t)(w - (char*)d_ws), ws_size);
    return;
  }

  // 1. weight prep + x->bf16 + decay poly coeffs
  prep_k<<<dim3(30728), 256, 0, stream>>>(x, W_in_f, W_in_b, Wx_f, Wx_b, Wdt_f, Wdt_b,
                                          Wout_f, Wout_b, Alog_f, Alog_b, bdt_f, bdt_b,
                                          W1cat, Wxpad, Wdtb, Woutcat, A2, bdtcat, xbf, Cf);
  // 2. GEMM1 (ring-4 counted vmcnt): xz(8192x4096) = xbf * W1cat^T; silu fused on z-columns
  gemm_ring<4><<<dim3(64,32,1), 256, 0, stream>>>(xbf, W1cat, xz, nullptr, nullptr,
                                                  512, 512, 512, 4096, 0, 0, 0, 0);
  // 3. depthwise conv + SiLU -> xbc(8192x2048)  (reads x-columns only)
  conv_silu_k<<<dim3(8192), 256, 0, stream>>>(xz, convw_f, convb_f, convw_b, convb_b, xbc);
  // 4. proj (ring): per dir, proj(8192x128) = xbc[:,dir] * Wxpad^T + fp32 B/C side-write
  gemm_ring<3><<<dim3(64,1,2), 256, 0, stream>>>(xbc, Wxpad, proj, nullptr, BCf,
                                                 1024, 2048, 1024, 128,
                                                 1024, 131072, 1048576, 0);
  // 5. dt (ring, NK=1): per dir, dt(8192x1024) = softplus(proj[:, :64] * Wdtb^T + bdt)
  gemm_ring<1><<<dim3(64,8,2), 256, 0, stream>>>(proj, Wdtb, dtb, bdtcat, nullptr,
                                                 64, 128, 64, 1024,
                                                 1048576, 65536, 8388608, 1024);
  // 6-8. chunked selective scan + gating -> ybuf(8192x2048)
  scan1_k<<<dim3(4,NCHUNK,8), 256, 0, stream>>>(dtb, xbc, BCf, Cf, hloc, Ssum);
  scan2_k<<<dim3(512), 256, 0, stream>>>(A2, Ssum, hloc);
  scan3_k<<<dim3(4,NCHUNK,8), 256, 0, stream>>>(dtb, xbc, BCf, Cf, hloc, xz, D_f, D_b, ybuf);
  // 9. GEMM3 (ring): out(8192x512,f32) = ybuf * Woutcat^T  (f+b summed via K)
  gemm_ring<2><<<dim3(64,4,1), 256, 0, stream>>>(ybuf, Woutcat, d_out, nullptr, nullptr,
                                                 2048, 2048, 2048, 512, 0, 0, 0, 0);
}

// Round 18
// 316.200 us; speedup vs baseline: 1.1355x; 1.1355x over previous
//
#include <hip/hip_runtime.h>
#include <hip/hip_bf16.h>
#include <cstdint>
#include <cstdio>

typedef float f32x4 __attribute__((ext_vector_type(4)));
typedef float f32x2 __attribute__((ext_vector_type(2)));
typedef short s16x8 __attribute__((ext_vector_type(8)));   // 8 bf16 (4 VGPRs) MFMA operand
typedef unsigned int u32x2 __attribute__((ext_vector_type(2)));

__device__ __forceinline__ float us2f(unsigned short u){
  union { unsigned int i; float f; } v; v.i = ((unsigned int)u) << 16; return v.f;
}
__device__ __forceinline__ unsigned short f2us(float f){   // RNE f32->bf16
  union { float f; unsigned int i; } v; v.f = f;
  unsigned int r = v.i + 0x7fffu + ((v.i >> 16) & 1u);
  return (unsigned short)(r >> 16);
}
// direct global->LDS DMA, 16B per lane; LDS dest must be linear (base + lane*16)
__device__ __forceinline__ void gload_lds16(const void* g, void* l){
  __builtin_amdgcn_global_load_lds(
      (const __attribute__((address_space(1))) unsigned int*)g,
      (__attribute__((address_space(3))) unsigned int*)l, 16, 0, 0);
}

// Decay poly constant term: e^y ~= K0 + c1*y ... (Taylor at y0=-0.18, deg 3), y = w*dt in [-0.36,0]
#define PK0 0.999962f

// ---------------- prep: cast/concat weights to bf16 (row-major, coalesced), poly coeffs --------
__global__ __launch_bounds__(256)
void prep_k(const float* __restrict__ x,
            const float* __restrict__ W_in_f, const float* __restrict__ W_in_b,
            const float* __restrict__ Wx_f,   const float* __restrict__ Wx_b,
            const float* __restrict__ Wdt_f,  const float* __restrict__ Wdt_b,
            const float* __restrict__ Wout_f, const float* __restrict__ Wout_b,
            const float* __restrict__ Alog_f, const float* __restrict__ Alog_b,
            const float* __restrict__ bdt_f,  const float* __restrict__ bdt_b,
            unsigned short* __restrict__ W1cat, unsigned short* __restrict__ Wxpad,
            unsigned short* __restrict__ Wdtb,  unsigned short* __restrict__ Woutcat,
            float* __restrict__ A2, float* __restrict__ bdtcat,
            unsigned short* __restrict__ xbf, float* __restrict__ Cf)
{
  long i = (long)blockIdx.x * 256 + threadIdx.x;
  if (i < 4194304) {            // xbf = bf16(x), 8192x512
    xbf[i] = f2us(x[i]); return;
  }
  i -= 4194304;
  if (i < 2097152) {            // W1cat[n][k], 4096x512 (f rows 0-2047, b rows 2048-4095)
    int n = (int)(i >> 9), k = (int)(i & 511);
    float v = (n < 2048) ? W_in_f[(long)n*512 + k] : W_in_b[(long)(n-2048)*512 + k];
    W1cat[i] = f2us(v); return;
  }
  i -= 2097152;
  if (i < 262144) {             // Wxpad[dir][128][1024], rows>=96 zero
    int dir = (int)(i >> 17); long r = i & 131071; int n = (int)(r >> 10), k = (int)(r & 1023);
    const float* Wx = dir ? Wx_b : Wx_f;
    Wxpad[(long)dir*131072 + r] = f2us(n < 96 ? Wx[(long)n*1024 + k] : 0.f); return;
  }
  i -= 262144;
  if (i < 131072) {             // Wdtb[dir][1024][64]
    int dir = (int)(i >> 16); long r = i & 65535;
    Wdtb[i] = f2us((dir ? Wdt_b : Wdt_f)[r]); return;
  }
  i -= 131072;
  if (i < 1048576) {            // Woutcat[n][2048]: k<1024 from f, else b
    int n = (int)(i >> 11), k = (int)(i & 2047);
    float v = (k < 1024) ? Wout_f[(long)n*1024 + k] : Wout_b[(long)n*1024 + (k-1024)];
    Woutcat[i] = f2us(v); return;
  }
  i -= 1048576;
  if (i < 32768) {              // A2[dir][m][d] = -exp(Alog[d][m]) * log2(e)  (scan2 only)
    int dir = (int)(i >> 14); long r = i & 16383; int m = (int)(r >> 4), d = (int)(r & 15);
    const float* Al = dir ? Alog_b : Alog_f;
    A2[i] = -__expf(Al[(long)d*1024 + m]) * 1.4426950408889634f; return;
  }
  i -= 32768;
  if (i < 2048) {               // bdtcat[dir][1024]
    int dir = (int)(i >> 10), m = (int)(i & 1023);
    bdtcat[i] = (dir ? bdt_b : bdt_f)[m]; return;
  }
  i -= 2048;
  if (i < 98304) {              // Cf[dir][m][48]: decay poly coeffs c1[16],c2[16],c3[16]
    int dir = (int)(i / 49152); long r = i % 49152;
    int m = (int)(r / 48), j = (int)(r % 48);
    int k = j >> 4, d = j & 15;
    const float* Al = dir ? Alog_b : Alog_f;
    const float w = -__expf(Al[(long)d*1024 + m]);     // dA = exp(w*dt), w in [-1.7,-0.6]
    float c;
    if (k == 0)      c = 0.999150f * w;                // e^y Taylor@-0.18 deg-3 coeffs
    else if (k == 1) c = 0.492809f * w * w;
    else             c = 0.139212f * w * w * w;
    Cf[(long)dir*49152 + (long)m*48 + (k << 4) + d] = c;
    return;
  }
}

// ---------------- 256x256 bf16 MFMA GEMM (GEMM1): 512 threads, 8 waves (2x4), BK=64, DBUF ------
// OUT_MODE 4: silu on z-columns ((col>>10)&1).
template<int OUT_MODE>
__global__ __launch_bounds__(512, 1)
void gemm_big(const unsigned short* __restrict__ Ap, const unsigned short* __restrict__ Bp,
              unsigned short* __restrict__ Cp,
              int K, int lda, int ldb, int ldc)
{
  const int tid = threadIdx.x;
  const int bm  = blockIdx.x, bn = blockIdx.y;

  __shared__ __align__(16) unsigned short Ash[2][256][64];   // 32KB per buf
  __shared__ __align__(16) unsigned short Bsh[2][256][64];

  const int wave = tid >> 6, lane = tid & 63;
  const int wr = (wave >> 2) << 7;          // 0 / 128
  const int wc = (wave & 3) << 6;           // 0 / 64 / 128 / 192
  const int fr = lane & 15, fs = lane >> 4;

  // staging: 4 rounds x 512 threads x 16B cover one 256x64 tile per matrix
  const int rr  = tid >> 3;                 // row 0..63 (+64/round)
  const int csp = tid & 7;                  // linear LDS col-slot
  const int csg = ((csp ^ (rr & 7)) << 3);  // pre-swizzled source col (elements)

  const long abase = (long)(bm*256 + rr)*lda + csg;
  const long bbase = (long)(bn*256 + rr)*ldb + csg;

  f32x4 acc[8][4];
  #pragma unroll
  for (int i=0;i<8;i++)
    #pragma unroll
    for (int j=0;j<4;j++) acc[i][j] = (f32x4){0.f,0.f,0.f,0.f};

  const int NK = K >> 6;

  auto stage = [&](int buf, int ks){
    const long k0 = (long)ks << 6;
    #pragma unroll
    for (int r=0;r<4;r++){
      gload_lds16(Ap + abase + (long)(r*64)*lda + k0, &Ash[buf][rr + r*64][csp << 3]);
      gload_lds16(Bp + bbase + (long)(r*64)*ldb + k0, &Bsh[buf][rr + r*64][csp << 3]);
    }
  };
  auto compute = [&](int buf){
    #pragma unroll
    for (int sub=0; sub<2; ++sub){
      s16x8 bfv[4];
      #pragma unroll
      for (int j=0;j<4;j++){
        const int br = wc + j*16 + fr;
        bfv[j] = *(const s16x8*)&Bsh[buf][br][(((sub<<2)+fs) ^ (fr&7)) << 3];
      }
      #pragma unroll
      for (int i=0;i<8;i++){
        const int ar = wr + i*16 + fr;
        const s16x8 af = *(const s16x8*)&Ash[buf][ar][(((sub<<2)+fs) ^ (fr&7)) << 3];
        #pragma unroll
        for (int j=0;j<4;j++)
          acc[i][j] = __builtin_amdgcn_mfma_f32_16x16x32_bf16(bfv[j], af, acc[i][j], 0, 0, 0);
      }
    }
  };

  stage(0, 0);
  int cur = 0;
  for (int ks = 0; ks < NK; ++ks){
    __syncthreads();                       // buf[cur] landed; prior reads of buf[cur^1] retired
    if (ks + 1 < NK) stage(cur ^ 1, ks + 1);
    compute(cur);
    cur ^= 1;
  }

  // epilogue — swapped D layout: row = lane&15 (i-tile), cols = (lane>>4)*4 + e (j-tile)
  #pragma unroll
  for (int i=0;i<8;i++){
    const int row = bm*256 + wr + i*16 + fr;
    #pragma unroll
    for (int j=0;j<4;j++){
      const int c0 = bn*256 + wc + j*16 + (fs << 2);
      f32x4 v = acc[i][j];
      if (OUT_MODE == 4 && ((c0 >> 10) & 1)){
        #pragma unroll
        for (int e=0;e<4;e++) v[e] = v[e] / (1.f + __expf(-v[e]));   // silu(z) fused
      }
      u32x2 o;
      o[0] = (unsigned int)f2us(v[0]) | ((unsigned int)f2us(v[1]) << 16);
      o[1] = (unsigned int)f2us(v[2]) | ((unsigned int)f2us(v[3]) << 16);
      *(u32x2*)(Cp + (long)row*ldc + c0) = o;
    }
  }
}

// ---------------- bf16 MFMA GEMM: C(MxN) = A(MxK) * B(NxK)^T, 128x128 tile, BK=64 ----------------
// OUT_MODE: 0 = bf16, 1 = bf16 softplus(acc+bias[col]), 2 = f32,
//           3 = bf16 + fp32 B/C side-write, 4 = bf16 with silu applied iff (col>>10)&1
template<int OUT_MODE, int DBUF>
__global__ __launch_bounds__(256)
void gemm_bt(const unsigned short* __restrict__ Ap, const unsigned short* __restrict__ Bp,
             void* __restrict__ Cp, const float* __restrict__ biasp,
             float* __restrict__ bcf,
             int K, int lda, int ldb, int ldc,
             long az, long bz, long cz, int biasz)
{
  const int z   = blockIdx.z;
  const int tid = threadIdx.x;
  const int bm  = blockIdx.x, bn = blockIdx.y;

  __shared__ __align__(16) unsigned short Ash[1+DBUF][128][64];   // 16KB each buf
  __shared__ __align__(16) unsigned short Bsh[1+DBUF][128][64];

  const int wave = tid >> 6, lane = tid & 63;
  const int wr = (wave >> 1) << 6, wc = (wave & 1) << 6;
  const int fr = lane & 15, fs = lane >> 4;

  const int rr  = tid >> 3;                 // row 0..31 (+32/round)
  const int csp = tid & 7;                  // linear LDS col-slot
  const int csg = ((csp ^ (rr & 7)) << 3);  // pre-swizzled source col (elements)

  const unsigned short* Ag = Ap + (long)z * az;
  const unsigned short* Bg = Bp + (long)z * bz;

  const long abase = (long)(bm*128 + rr)*lda + csg;
  const long bbase = (long)(bn*128 + rr)*ldb + csg;

  f32x4 acc[4][4];
  #pragma unroll
  for (int i=0;i<4;i++)
    #pragma unroll
    for (int j=0;j<4;j++) acc[i][j] = (f32x4){0.f,0.f,0.f,0.f};

  const int NK = K >> 6;

  auto stage = [&](int buf, int ks){
    const long k0 = (long)ks << 6;
    #pragma unroll
    for (int r=0;r<4;r++){
      gload_lds16(Ag + abase + (long)(r*32)*lda + k0, &Ash[buf][rr + r*32][csp << 3]);
      gload_lds16(Bg + bbase + (long)(r*32)*ldb + k0, &Bsh[buf][rr + r*32][csp << 3]);
    }
  };
  auto compute = [&](int buf){
    #pragma unroll
    for (int sub=0; sub<2; ++sub){
      s16x8 af[4], bfv[4];
      #pragma unroll
      for (int i=0;i<4;i++){
        const int ar = wr + i*16 + fr;
        af[i]  = *(const s16x8*)&Ash[buf][ar][(((sub<<2)+fs) ^ (fr&7)) << 3];
        const int br = wc + i*16 + fr;
        bfv[i] = *(const s16x8*)&Bsh[buf][br][(((sub<<2)+fs) ^ (fr&7)) << 3];
      }
      #pragma unroll
      for (int i=0;i<4;i++)
        #pragma unroll
        for (int j=0;j<4;j++)
          acc[i][j] = __builtin_amdgcn_mfma_f32_16x16x32_bf16(bfv[j], af[i], acc[i][j], 0, 0, 0);
    }
  };

  if (DBUF){
    stage(0, 0);
    int cur = 0;
    for (int ks = 0; ks < NK; ++ks){
      __syncthreads();                     // buf[cur] landed; prior reads of buf[cur^1] retired
      if (ks + 1 < NK) stage(cur ^ 1, ks + 1);   // issue next tile BEFORE compute
      compute(cur);
      cur ^= 1;
    }
  } else {
    for (int ks = 0; ks < NK; ++ks){
      __syncthreads();
      stage(0, ks);
      __syncthreads();
      compute(0);
    }
  }

  // epilogue — swapped D layout: row = lane&15 (within i-tile), cols = (lane>>4)*4 + e (j-tile)
  #pragma unroll
  for (int i=0;i<4;i++){
    const int row = bm*128 + wr + i*16 + fr;
    #pragma unroll
    for (int j=0;j<4;j++){
      const int c0 = bn*128 + wc + j*16 + (fs << 2);
      f32x4 v = acc[i][j];
      const long cbase = (long)z*cz + (long)row*ldc + c0;
      if (OUT_MODE == 2){
        *(f32x4*)((float*)Cp + cbase) = v;
      } else if (OUT_MODE == 1){
        const f32x4 b4 = *(const f32x4*)(biasp + z*biasz + c0);
        u32x2 o;
        unsigned short s[4];
        #pragma unroll
        for (int e=0;e<4;e++){
          float t = v[e] + b4[e];
          t = fmaxf(t, 0.f) + log1pf(__expf(-fabsf(t)));   // softplus, stable
          s[e] = f2us(t);
        }
        o[0] = (unsigned int)s[0] | ((unsigned int)s[1] << 16);
        o[1] = (unsigned int)s[2] | ((unsigned int)s[3] << 16);
        *(u32x2*)((unsigned short*)Cp + cbase) = o;
      } else {
        u32x2 o;
        o[0] = (unsigned int)f2us(v[0]) | ((unsigned int)f2us(v[1]) << 16);
        o[1] = (unsigned int)f2us(v[2]) | ((unsigned int)f2us(v[3]) << 16);
        *(u32x2*)((unsigned short*)Cp + cbase) = o;
        if (OUT_MODE == 3 && c0 >= 64 && c0 < 96){
          *(f32x4*)(bcf + ((long)z*8192 + row)*32 + (c0 - 64)) = v;
        }
      }
    }
  }
}

// ---------------- depthwise causal/anticausal conv (K=4) + SiLU, 8 channels/thread -------------
__global__ __launch_bounds__(256)
void conv_silu_k(const unsigned short* __restrict__ xz,
                 const float* __restrict__ wf, const float* __restrict__ cbf,
                 const float* __restrict__ wb, const float* __restrict__ cbb,
                 unsigned short* __restrict__ xbc)
{
  const int tid = threadIdx.x;
  const long tok = blockIdx.x;                       // 0..8191
  const int l   = (int)(tok & 2047);
  const int dir = tid >> 7;
  const int mg  = (tid & 127) << 3;                  // base of 8 contiguous channels
  const float* w  = dir ? wb  : wf;
  const float* cb = dir ? cbb : cbf;
  const long rowb = tok << 12;                       // *4096
  const int  xcol = (dir << 11) + mg;                // xb_f cols [0,1024), xb_b [2048,3072)

  f32x4 wv[8];
  #pragma unroll
  for (int e=0;e<8;e++) wv[e] = *(const f32x4*)(w + (mg + e)*4);
  const f32x4 cb0 = *(const f32x4*)(cb + mg);
  const f32x4 cb1 = *(const f32x4*)(cb + mg + 4);

  float acc[8];
  #pragma unroll
  for (int e=0;e<4;e++){ acc[e]=cb0[e]; acc[4+e]=cb1[e]; }

  #pragma unroll
  for (int k=0;k<4;k++){
    const int off = dir ? (3 - k) : (k - 3);         // pos - l
    const int pos = l + off;
    if (pos >= 0 && pos < 2048){                     // wave-uniform predicate
      const s16x8 xv = *(const s16x8*)(xz + rowb + ((long)off << 12) + xcol);
      #pragma unroll
      for (int e=0;e<8;e++)
        acc[e] = __builtin_fmaf(wv[e][k], us2f((unsigned short)xv[e]), acc[e]);
    }
  }
  s16x8 out;
  #pragma unroll
  for (int e=0;e<8;e++){
    const float s = acc[e] / (1.f + __expf(-acc[e]));
    out[e] = (short)f2us(s);
  }
  *(s16x8*)(xbc + tok*2048 + (dir << 10) + mg) = out;
}

// ---------------- chunked selective scan: 64 chunks x 32 steps, 1 channel/thread ---------------
#define SCHUNK 32
#define NCHUNK 64

// pass 1: per-chunk local scan + S = sum(dt). Packed f32x2 math; prefetch depth 2.
__global__ __launch_bounds__(256)
void scan1_k(const unsigned short* __restrict__ dtb, const unsigned short* __restrict__ xbc,
             const float* __restrict__ BCf, const float* __restrict__ Cf,
             unsigned short* __restrict__ hloc, float* __restrict__ Ssum)
{
  const int tidx = threadIdx.x;
  const int cb = blockIdx.x, c = blockIdx.y, bz = blockIdx.z;
  const int b = bz >> 1, dir = bz & 1;
  const int m = cb*256 + tidx;

  f32x2 C1v[8], C2v[8], C3v[8];
  { const f32x4* p = (const f32x4*)(Cf + ((long)dir*1024 + m)*48);
    #pragma unroll
    for (int q=0;q<4;q++){
      f32x4 v1=p[q], v2=p[q+4], v3=p[q+8];
      C1v[2*q]   = (f32x2){v1[0], v1[1]};  C1v[2*q+1] = (f32x2){v1[2], v1[3]};
      C2v[2*q]   = (f32x2){v2[0], v2[1]};  C2v[2*q+1] = (f32x2){v2[2], v2[3]};
      C3v[2*q]   = (f32x2){v3[0], v3[1]};  C3v[2*q+1] = (f32x2){v3[2], v3[3]};
    } }
  const f32x2 k0v = {PK0, PK0};

  const int  l0 = dir ? (2047 - c*SCHUNK) : (c*SCHUNK);
  const int  ls = dir ? -1 : 1;
  const long tok0 = (long)b*2048 + l0;

  __shared__ float Bs[SCHUNK][16];
  if (tidx < 128){
    const int r = tidx >> 2, c4 = (tidx & 3) << 2;
    *(f32x4*)&Bs[r][c4] =
        *(const f32x4*)(BCf + ((long)dir*8192 + tok0 + (long)ls*r)*32 + c4);
  }
  __syncthreads();

  const long dstp = (long)ls*1024, xstp = (long)ls*2048;
  const unsigned short* dt0 = dtb + ((long)dir << 23) + tok0*1024 + m;
  const unsigned short* xv0 = xbc + tok0*2048 + (dir << 10) + m;
  const unsigned short* dt1 = dt0 + dstp;
  const unsigned short* xv1 = xv0 + xstp;

  f32x2 h2[8];
  #pragma unroll
  for (int p=0;p<8;p++) h2[p] = (f32x2){0.f, 0.f};
  float S = 0.f;

  auto body = [&](float dt, float xv, int t){
    S += dt;
    const float u = dt * xv;
    const float dt2 = dt*dt, dt3 = dt2*dt;
    const f32x2 dtv = {dt, dt}, dt2v = {dt2, dt2}, dt3v = {dt3, dt3}, uv = {u, u};
    const f32x2* b2 = (const f32x2*)&Bs[t][0];
    #pragma unroll
    for (int p=0;p<8;p++){
      f32x2 a = __builtin_elementwise_fma(C1v[p], dtv, k0v);
      a = __builtin_elementwise_fma(C2v[p], dt2v, a);
      a = __builtin_elementwise_fma(C3v[p], dt3v, a);
      h2[p] = __builtin_elementwise_fma(a, h2[p], uv * b2[p]);
    }
  };

  unsigned short dA = *dt0, xA = *xv0, dB = *dt1, xB = *xv1;   // steps t, t+1
  for (int t=0; t<SCHUNK; t+=2){
    const float dtA = us2f(dA), xvA = us2f(xA);
    dt0 += 2*dstp; xv0 += 2*xstp;
    dA = *dt0; xA = *xv0;                 // prefetch t+2 (edge reads stay inside d_ws)
    body(dtA, xvA, t);
    const float dtB = us2f(dB), xvB = us2f(xB);
    dt1 += 2*dstp; xv1 += 2*xstp;
    dB = *dt1; xB = *xv1;                 // prefetch t+3
    body(dtB, xvB, t+1);
  }
  const long o = (((long)bz * NCHUNK) + c)*1024 + m;
  s16x8 hv0, hv1;
  #pragma unroll
  for (int e=0;e<4;e++){
    hv0[2*e]   = (short)f2us(h2[e][0]);     hv0[2*e+1] = (short)f2us(h2[e][1]);
    hv1[2*e]   = (short)f2us(h2[4+e][0]);   hv1[2*e+1] = (short)f2us(h2[4+e][1]);
  }
  *(s16x8*)(hloc + (o << 4))     = hv0;
  *(s16x8*)(hloc + (o << 4) + 8) = hv1;
  Ssum[o] = S;
}

// pass 2: chunk recurrence; rewrites hloc in place with h_start per chunk (bf16)
__global__ __launch_bounds__(256)
void scan2_k(const float* __restrict__ A2, const float* __restrict__ Ssum,
             unsigned short* __restrict__ hloc)
{
  const long idx = (long)blockIdx.x*256 + threadIdx.x;   // 8*16384
  const long bz = idx >> 14; const int r = (int)(idx & 16383);
  const int dir = (int)(bz & 1);
  const float a2 = A2[((long)dir << 14) + r];
  const long base = bz * NCHUNK;
  float hs = 0.f;
  float hlN = us2f(hloc[base*16384 + r]);
  float SN  = Ssum[base*1024 + (r >> 4)];
  for (int c=0;c<NCHUNK;c++){
    const float hl = hlN, Sv = SN;
    const int cn = (c+1 < NCHUNK) ? c+1 : c;             // clamped prefetch
    hlN = us2f(hloc[(base+cn)*16384 + r]);
    SN  = Ssum[(base+cn)*1024 + (r >> 4)];
    const float P = __builtin_amdgcn_exp2f(a2 * Sv);     // range [-4,0]: keep HW exp2
    hloc[(base+c)*16384 + r] = f2us(hs);
    hs = __builtin_fmaf(P, hs, hl);
  }
}

// pass 3: full scan, fused +D*x, *pre-silu'd gate, bf16 y; packed f32x2; prefetch depth 2.
__global__ __launch_bounds__(256)
void scan3_k(const unsigned short* __restrict__ dtb, const unsigned short* __restrict__ xbc,
             const float* __restrict__ BCf, const float* __restrict__ Cf,
             const unsigned short* __restrict__ hstart, const unsigned short* __restrict__ xz,
             const float* __restrict__ D_f, const float* __restrict__ D_b,
             unsigned short* __restrict__ ybuf)
{
  const int tidx = threadIdx.x;
  const int cb = blockIdx.x, c = blockIdx.y, bz = blockIdx.z;
  const int b = bz >> 1, dir = bz & 1;
  const int m = cb*256 + tidx;

  f32x2 C1v[8], C2v[8], C3v[8];
  { const f32x4* p = (const f32x4*)(Cf + ((long)dir*1024 + m)*48);
    #pragma unroll
    for (int q=0;q<4;q++){
      f32x4 v1=p[q], v2=p[q+4], v3=p[q+8];
      C1v[2*q]   = (f32x2){v1[0], v1[1]};  C1v[2*q+1] = (f32x2){v1[2], v1[3]};
      C2v[2*q]   = (f32x2){v2[0], v2[1]};  C2v[2*q+1] = (f32x2){v2[2], v2[3]};
      C3v[2*q]   = (f32x2){v3[0], v3[1]};  C3v[2*q+1] = (f32x2){v3[2], v3[3]};
    } }
  const f32x2 k0v = {PK0, PK0};
  const float Dm = (dir ? D_b : D_f)[m];

  const int  l0 = dir ? (2047 - c*SCHUNK) : (c*SCHUNK);
  const int  ls = dir ? -1 : 1;
  const long tok0 = (long)b*2048 + l0;

  __shared__ float BC[SCHUNK][32];    // [t][0-15 B, 16-31 C]
  { const int r = tidx >> 3, c4 = (tidx & 7) << 2;
    *(f32x4*)&BC[r][c4] =
        *(const f32x4*)(BCf + ((long)dir*8192 + tok0 + (long)ls*r)*32 + c4); }

  f32x2 h2[8];
  { const long o = ((((long)bz*NCHUNK) + c)*1024 + m) << 4;
    s16x8 hv0 = *(const s16x8*)(hstart + o);
    s16x8 hv1 = *(const s16x8*)(hstart + o + 8);
    #pragma unroll
    for (int e=0;e<4;e++){
      h2[e]   = (f32x2){us2f((unsigned short)hv0[2*e]), us2f((unsigned short)hv0[2*e+1])};
      h2[4+e] = (f32x2){us2f((unsigned short)hv1[2*e]), us2f((unsigned short)hv1[2*e+1])};
    } }
  __syncthreads();

  const long dstp = (long)ls*1024, xstp = (long)ls*2048, zstp = (long)ls << 12;
  const unsigned short* dt0 = dtb + ((long)dir << 23) + tok0*1024 + m;
  const unsigned short* xv0 = xbc + tok0*2048 + (dir << 10) + m;
  const unsigned short* zp0 = xz  + (tok0 << 12) + (dir << 11) + 1024 + m;
  const unsigned short* dt1 = dt0 + dstp;
  const unsigned short* xv1 = xv0 + xstp;
  const unsigned short* zp1 = zp0 + zstp;
  unsigned short*       yp  = ybuf + tok0*2048 + (dir << 10) + m;

  auto body = [&](float dt, float xv, float gate, int t){
    const float u = dt * xv;
    const float dt2 = dt*dt, dt3 = dt2*dt;
    const f32x2 dtv = {dt, dt}, dt2v = {dt2, dt2}, dt3v = {dt3, dt3}, uv = {u, u};
    const f32x2* bc2 = (const f32x2*)&BC[t][0];    // B pairs [0..7], C pairs [8..15]
    f32x2 y2a = {0.f, 0.f}, y2b = {0.f, 0.f};
    #pragma unroll
    for (int p=0;p<8;p++){
      f32x2 a = __builtin_elementwise_fma(C1v[p], dtv, k0v);
      a = __builtin_elementwise_fma(C2v[p], dt2v, a);
      a = __builtin_elementwise_fma(C3v[p], dt3v, a);
      h2[p] = __builtin_elementwise_fma(a, h2[p], uv * bc2[p]);
      if (p & 1) y2b = __builtin_elementwise_fma(h2[p], bc2[8+p], y2b);
      else       y2a = __builtin_elementwise_fma(h2[p], bc2[8+p], y2a);
    }
    const float y = ((y2a[0] + y2a[1]) + (y2b[0] + y2b[1])) + Dm * xv;
    *yp = f2us(y * gate);
    yp += xstp;
  };

  unsigned short dA = *dt0, xA = *xv0, zA = *zp0;   // step t
  unsigned short dB = *dt1, xB = *xv1, zB = *zp1;   // step t+1
  for (int t=0; t<SCHUNK; t+=2){
    const float dtA = us2f(dA), xvA = us2f(xA), gA = us2f(zA);
    dt0 += 2*dstp; xv0 += 2*xstp; zp0 += 2*zstp;
    dA = *dt0; xA = *xv0; zA = *zp0;      // prefetch t+2 (edge reads stay inside d_ws)
    body(dtA, xvA, gA, t);
    const float dtB = us2f(dB), xvB = us2f(xB), gB = us2f(zB);
    dt1 += 2*dstp; xv1 += 2*xstp; zp1 += 2*zstp;
    dB = *dt1; xB = *xv1; zB = *zp1;      // prefetch t+3
    body(dtB, xvB, gB, t+1);
  }
}

// ---------------- host launcher ----------------------------------------------------------------
extern "C" void kernel_launch(void* const* d_in, const int* in_sizes, int n_in,
                              void* d_out, int out_size, void* d_ws, size_t ws_size,
                              hipStream_t stream)
{
  const float* x      = (const float*)d_in[0];
  const float* W_in_f = (const float*)d_in[1];
  const float* convw_f= (const float*)d_in[2];
  const float* convb_f= (const float*)d_in[3];
  const float* Alog_f = (const float*)d_in[4];
  const float* D_f    = (const float*)d_in[5];
  const float* Wx_f   = (const float*)d_in[6];
  const float* Wdt_f  = (const float*)d_in[7];
  const float* bdt_f  = (const float*)d_in[8];
  const float* Wout_f = (const float*)d_in[9];
  const float* W_in_b = (const float*)d_in[10];
  const float* convw_b= (const float*)d_in[11];
  const float* convb_b= (const float*)d_in[12];
  const float* Alog_b = (const float*)d_in[13];
  const float* D_b    = (const float*)d_in[14];
  const float* Wx_b   = (const float*)d_in[15];
  const float* Wdt_b  = (const float*)d_in[16];
  const float* bdt_b  = (const float*)d_in[17];
  const float* Wout_b = (const float*)d_in[18];

  char* w = (char*)d_ws;
  auto carve = [&](size_t bytes) -> char* {
    char* p = w; w += (bytes + 255) & ~(size_t)255; return p;
  };
  unsigned short* W1cat   = (unsigned short*)carve(4096ULL*512*2);
  unsigned short* Wxpad   = (unsigned short*)carve(2ULL*128*1024*2);
  unsigned short* Wdtb    = (unsigned short*)carve(2ULL*1024*64*2);
  unsigned short* Woutcat = (unsigned short*)carve(512ULL*2048*2);
  float*          A2      = (float*)carve(2ULL*1024*16*4);
  float*          bdtcat  = (float*)carve(2048ULL*4);
  float*          Cf      = (float*)carve(2ULL*1024*48*4);
  float*          BCf     = (float*)carve(2ULL*8192*32*4);
  unsigned short* xz      = (unsigned short*)carve(8192ULL*4096*2);
  unsigned short* xbc     = (unsigned short*)carve(8192ULL*2048*2);
  unsigned short* proj    = (unsigned short*)carve(2ULL*8192*128*2);
  unsigned short* dtb     = (unsigned short*)carve(2ULL*8192*1024*2);
  unsigned short* ybuf    = (unsigned short*)carve(8192ULL*2048*2);
  unsigned short* hloc    = (unsigned short*)carve(8ULL*NCHUNK*1024*16*2);
  float*          Ssum    = (float*)carve(8ULL*NCHUNK*1024*4);
  // xbf aliases ybuf: xbf lifetime = prep->GEMM1, ybuf lifetime = scan3->GEMM3 (disjoint)
  unsigned short* xbf     = ybuf;

  if ((size_t)(w - (char*)d_ws) > ws_size) {
    fprintf(stderr, "kernel_launch: ws too small (%zu needed, %zu given)\n",
            (size_t)(w - (char*)d_ws), ws_size);
    return;
  }

  // 1. weight prep + x->bf16 + decay poly coeffs
  prep_k<<<dim3(30728), 256, 0, stream>>>(x, W_in_f, W_in_b, Wx_f, Wx_b, Wdt_f, Wdt_b,
                                          Wout_f, Wout_b, Alog_f, Alog_b, bdt_f, bdt_b,
                                          W1cat, Wxpad, Wdtb, Woutcat, A2, bdtcat, xbf, Cf);
  // 2. GEMM1 (256^2 DBUF): xz(8192x4096) = xbf * W1cat^T; silu fused on z-columns
  gemm_big<4><<<dim3(32,16), 512, 0, stream>>>(xbf, W1cat, xz, 512, 512, 512, 4096);
  // 3. depthwise conv + SiLU -> xbc(8192x2048)  (reads x-columns only)
  conv_silu_k<<<dim3(8192), 256, 0, stream>>>(xz, convw_f, convb_f, convw_b, convb_b, xbc);
  // 4. proj (DBUF): per dir, proj(8192x128) = xbc[:,dir] * Wxpad^T + fp32 B/C side-write
  gemm_bt<3,1><<<dim3(64,1,2), 256, 0, stream>>>(xbc, Wxpad, proj, nullptr, BCf,
                                                 1024, 2048, 1024, 128,
                                                 1024, 131072, 1048576, 0);
  // 5. dt: per dir, dt(8192x1024) = softplus(proj[:, :64] * Wdtb^T + bdt)
  gemm_bt<1,0><<<dim3(64,8,2), 256, 0, stream>>>(proj, Wdtb, dtb, bdtcat, nullptr,
                                                 64, 128, 64, 1024,
                                                 1048576, 65536, 8388608, 1024);
  // 6-8. chunked selective scan + gating -> ybuf(8192x2048)
  scan1_k<<<dim3(4,NCHUNK,8), 256, 0, stream>>>(dtb, xbc, BCf, Cf, hloc, Ssum);
  scan2_k<<<dim3(512), 256, 0, stream>>>(A2, Ssum, hloc);
  scan3_k<<<dim3(4,NCHUNK,8), 256, 0, stream>>>(dtb, xbc, BCf, Cf, hloc, xz, D_f, D_b, ybuf);
  // 9. GEMM3 (DBUF): out(8192x512,f32) = ybuf * Woutcat^T  (f+b summed via K)
  gemm_bt<2,1><<<dim3(64,4,1), 256, 0, stream>>>(ybuf, Woutcat, d_out, nullptr, nullptr,
                                                 2048, 2048, 2048, 512, 0, 0, 0, 0);
}